// Round 16
// baseline (960.794 us; speedup 1.0000x reference)
//
#include <hip/hip_runtime.h>
#include <hip/hip_fp16.h>
#include <math.h>

#define N_NODES 50000
#define N_EDGES 1600000
#define N_GRAPHS 512
#define F_IN 9
#define H 64
#define N_BUCKETS ((N_NODES + 255) >> 8)     // 196
#define EPB 8192
#define N_SBLK ((N_EDGES + EPB - 1) / EPB)   // 196
#define FINE_CAP 10240                        // mean 8192, sd ~90 -> +22 sd

typedef _Float16 f16x8 __attribute__((ext_vector_type(8)));
typedef float f32x4 __attribute__((ext_vector_type(4)));

__device__ __forceinline__ void pack_weights_body(
        const float* __restrict__ w1a, const float* __restrict__ w1b,
        const float* __restrict__ w2a, const float* __restrict__ w2b,
        const float* __restrict__ wr1,
        __half* __restrict__ pk1Ah, __half* __restrict__ pk1Al,
        __half* __restrict__ pk1Bh, __half* __restrict__ pk1Bl,
        __half* __restrict__ pkAh, __half* __restrict__ pkAl,
        __half* __restrict__ pkBh, __half* __restrict__ pkBl,
        __half* __restrict__ pkRh, __half* __restrict__ pkRl) {
    int t = threadIdx.x;
    for (int i = t; i < 2048; i += 256) {      // w1a: [64][9], K=32 zero-pad
        int j = i & 7, l = (i >> 3) & 63, tt = i >> 9;
        int q = l >> 4, n = l & 15;
        int k = q * 8 + j;
        float v = (k < F_IN) ? w1a[(tt * 16 + n) * F_IN + k] : 0.f;
        __half h = __float2half(v);
        pk1Ah[i] = h; pk1Al[i] = __float2half(v - __half2float(h));
    }
    for (int i = t; i < 4096; i += 256) {
        int j = i & 7, l = (i >> 3) & 63, c = (i >> 9) & 1, tt = i >> 10;
        int q = l >> 4, n = l & 15;
        int src = (tt * 16 + n) * H + c * 32 + q * 8 + j;
        float v1 = w1b[src], wa = w2a[src], wb = w2b[src];
        __half h1 = __float2half(v1), ah = __float2half(wa), bh = __float2half(wb);
        pk1Bh[i] = h1; pk1Bl[i] = __float2half(v1 - __half2float(h1));
        pkAh[i] = ah; pkAl[i] = __float2half(wa - __half2float(ah));
        pkBh[i] = bh; pkBl[i] = __float2half(wb - __half2float(bh));
    }
    for (int i = t; i < 2048; i += 256) {
        int j = i & 7, l = (i >> 3) & 63, c = (i >> 9) & 1, tt = i >> 10;
        int q = l >> 4, n = l & 15;
        float wr = wr1[(tt * 16 + n) * H + c * 32 + q * 8 + j];
        __half rh = __float2half(wr);
        pkRh[i] = rh; pkRl[i] = __float2half(wr - __half2float(rh));
    }
}

// ---------- bucket scatter (fixed-capacity buckets); block 0 packs weights ----------
__global__ void bucket_scatter(const int* __restrict__ ei,
                               const float* __restrict__ ea,
                               int* __restrict__ bnext,
                               uint2* __restrict__ ebuk,
                               const float* __restrict__ w1a,
                               const float* __restrict__ w1b,
                               const float* __restrict__ w2a,
                               const float* __restrict__ w2b,
                               const float* __restrict__ wr1,
                               __half* pk1Ah, __half* pk1Al,
                               __half* pk1Bh, __half* pk1Bl,
                               __half* pkAh, __half* pkAl,
                               __half* pkBh, __half* pkBl,
                               __half* pkRh, __half* pkRl) {
    if (blockIdx.x == 0) {
        pack_weights_body(w1a, w1b, w2a, w2b, wr1, pk1Ah, pk1Al, pk1Bh, pk1Bl,
                          pkAh, pkAl, pkBh, pkBl, pkRh, pkRl);
        return;
    }
    __shared__ int cnt[N_BUCKETS];
    __shared__ int gbase[N_BUCKETS];
    for (int i = threadIdx.x; i < N_BUCKETS; i += 256) cnt[i] = 0;
    __syncthreads();
    int base = (blockIdx.x - 1) * EPB;
    int rk[32];
#pragma unroll
    for (int j = 0; j < 32; ++j) {
        int e = base + j * 256 + threadIdx.x;
        rk[j] = -1;
        if (e < N_EDGES) {
            int d = ei[N_EDGES + e];
            int b = d >> 8;
            int r = atomicAdd(&cnt[b], 1);
            rk[j] = (b << 21) | ((d & 255) << 13) | r;
        }
    }
    __syncthreads();
    for (int i = threadIdx.x; i < N_BUCKETS; i += 256)
        gbase[i] = cnt[i] ? atomicAdd(&bnext[i], cnt[i]) : 0;
    __syncthreads();
#pragma unroll
    for (int j = 0; j < 32; ++j) {
        if (rk[j] < 0) continue;
        int e = base + j * 256 + threadIdx.x;
        int b = rk[j] >> 21, dl = (rk[j] >> 13) & 255, r = rk[j] & 8191;
        int slot = gbase[b] + r;
        if (slot >= FINE_CAP) continue;
        unsigned pay = ((unsigned)ei[e] << 16) |
                       (unsigned)__half_as_ushort(__float2half(ea[e]));
        ebuk[(size_t)b * FINE_CAP + slot] = make_uint2(pay, (unsigned)dl);
    }
}

#define UNPACK_ATTR(P) __half2float(__ushort_as_half((unsigned short)((P) & 0xffffu)))

// ---------- conv1 aggregation, bucket-centric: LDS acc[256][9], write xs ----------
__global__ void __launch_bounds__(1024)
aggbucket1(const float* __restrict__ x,
           const int* __restrict__ bnext,
           const uint2* __restrict__ ebuk,
           const float* __restrict__ e1w,
           const float* __restrict__ e1b,
           float* __restrict__ xs) {
    __shared__ float acc[256][F_IN];
    int tid = threadIdx.x;
    for (int i = tid; i < 256 * F_IN; i += 1024) ((float*)acc)[i] = 0.f;
    __syncthreads();
    int b = blockIdx.x;
    int count = bnext[b]; if (count > FINE_CAP) count = FINE_CAP;
    const uint2* eb = ebuk + (size_t)b * FINE_CAP;
    int wv = tid >> 6, lane = tid & 63;
    int e = lane / 9;          // 0..7 (lane 63 -> 7, inactive)
    int f = lane - e * 9;      // 0..8
    bool act = e < 7;
    float wf = act ? e1w[f] : 0.f;
    float bf = act ? e1b[f] : 0.f;
    int chunk = (count + 15) >> 4;
    int lo = wv * chunk;
    int hi = lo + chunk; if (hi > count) hi = count;
    int j = lo;
    for (; j + 28 <= hi; j += 28) {            // 4 rounds x 7 edges in flight
        uint2 p0 = eb[j + e], p1 = eb[j + 7 + e];
        uint2 p2 = eb[j + 14 + e], p3 = eb[j + 21 + e];
        float v0 = x[(p0.x >> 16) * F_IN + f];
        float v1 = x[(p1.x >> 16) * F_IN + f];
        float v2 = x[(p2.x >> 16) * F_IN + f];
        float v3 = x[(p3.x >> 16) * F_IN + f];
        if (act) {
            atomicAdd(&acc[p0.y][f], fmaxf(v0 + UNPACK_ATTR(p0.x) * wf + bf, 0.f));
            atomicAdd(&acc[p1.y][f], fmaxf(v1 + UNPACK_ATTR(p1.x) * wf + bf, 0.f));
            atomicAdd(&acc[p2.y][f], fmaxf(v2 + UNPACK_ATTR(p2.x) * wf + bf, 0.f));
            atomicAdd(&acc[p3.y][f], fmaxf(v3 + UNPACK_ATTR(p3.x) * wf + bf, 0.f));
        }
    }
    for (; j < hi; j += 7) {
        int idx = j + e;
        if (act && idx < hi) {
            uint2 p = eb[idx];
            float v = x[(p.x >> 16) * F_IN + f];
            atomicAdd(&acc[p.y][f], fmaxf(v + UNPACK_ATTR(p.x) * wf + bf, 0.f));
        }
    }
    __syncthreads();
    for (int i = tid; i < 256 * 32; i += 1024) {
        int n = i >> 5, c = i & 31;
        int g = (b << 8) + n;
        if (g < N_NODES)
            xs[(size_t)g * 32 + c] = (c < F_IN) ? x[g * F_IN + c] + acc[n][c] : 0.f;
    }
}

// ---------- conv2 aggregation, bucket-centric (phase = one 3.2MB half, L2-resident);
// fuses h = h1 + agg, writes htot slice ----------
__global__ void __launch_bounds__(1024)
aggbucket2(const __half* __restrict__ harr,
           const int* __restrict__ bnext,
           const uint2* __restrict__ ebuk,
           const float* __restrict__ ew,
           const float* __restrict__ ebias,
           float* __restrict__ htot, int foff) {
    __shared__ float acc[256][32];
    int tid = threadIdx.x;
    for (int i = tid; i < 8192; i += 1024) ((float*)acc)[i] = 0.f;
    __syncthreads();
    int b = blockIdx.x;
    int count = bnext[b]; if (count > FINE_CAP) count = FINE_CAP;
    const uint2* eb = ebuk + (size_t)b * FINE_CAP;
    int wv = tid >> 6, lane = tid & 63;
    int half = lane >> 5, fh = lane & 31;
    float wf = ew[fh], bf = ebias[fh];
    int chunk = (count + 15) >> 4;
    int lo = wv * chunk;
    int hi = lo + chunk; if (hi > count) hi = count;
    int j = lo;
#define EDGE1(P) do {                                                          \
        float v_ = __half2float(harr[((P).x >> 16) * 32 + fh]);                \
        atomicAdd(&acc[(P).y][fh],                                             \
                  fmaxf(v_ + UNPACK_ATTR((P).x) * wf + bf, 0.f));              \
    } while (0)
    for (; j + 16 <= hi; j += 16) {            // 8 gathers in flight, 16 edges
        uint2 p0 = eb[j +  0 + half], p1 = eb[j +  2 + half];
        uint2 p2 = eb[j +  4 + half], p3 = eb[j +  6 + half];
        uint2 p4 = eb[j +  8 + half], p5 = eb[j + 10 + half];
        uint2 p6 = eb[j + 12 + half], p7 = eb[j + 14 + half];
        float v0 = __half2float(harr[(p0.x >> 16) * 32 + fh]);
        float v1 = __half2float(harr[(p1.x >> 16) * 32 + fh]);
        float v2 = __half2float(harr[(p2.x >> 16) * 32 + fh]);
        float v3 = __half2float(harr[(p3.x >> 16) * 32 + fh]);
        float v4 = __half2float(harr[(p4.x >> 16) * 32 + fh]);
        float v5 = __half2float(harr[(p5.x >> 16) * 32 + fh]);
        float v6 = __half2float(harr[(p6.x >> 16) * 32 + fh]);
        float v7 = __half2float(harr[(p7.x >> 16) * 32 + fh]);
        atomicAdd(&acc[p0.y][fh], fmaxf(v0 + UNPACK_ATTR(p0.x) * wf + bf, 0.f));
        atomicAdd(&acc[p1.y][fh], fmaxf(v1 + UNPACK_ATTR(p1.x) * wf + bf, 0.f));
        atomicAdd(&acc[p2.y][fh], fmaxf(v2 + UNPACK_ATTR(p2.x) * wf + bf, 0.f));
        atomicAdd(&acc[p3.y][fh], fmaxf(v3 + UNPACK_ATTR(p3.x) * wf + bf, 0.f));
        atomicAdd(&acc[p4.y][fh], fmaxf(v4 + UNPACK_ATTR(p4.x) * wf + bf, 0.f));
        atomicAdd(&acc[p5.y][fh], fmaxf(v5 + UNPACK_ATTR(p5.x) * wf + bf, 0.f));
        atomicAdd(&acc[p6.y][fh], fmaxf(v6 + UNPACK_ATTR(p6.x) * wf + bf, 0.f));
        atomicAdd(&acc[p7.y][fh], fmaxf(v7 + UNPACK_ATTR(p7.x) * wf + bf, 0.f));
    }
    for (; j + 2 <= hi; j += 2) {
        uint2 p = eb[j + half];
        EDGE1(p);
    }
    if (j < hi && half == 0) {
        uint2 p = eb[j];
        EDGE1(p);
    }
#undef EDGE1
    __syncthreads();
    for (int i = tid; i < 8192; i += 1024) {
        int n = i >> 5, c = i & 31;
        int g = (b << 8) + n;
        if (g < N_NODES)
            htot[(size_t)g * 64 + foff + c] =
                __half2float(harr[(size_t)g * 32 + c]) + acc[n][c];
    }
}

__device__ __forceinline__ void split8(const float* __restrict__ v,
                                       f16x8& hi, f16x8& lo) {
#pragma unroll
    for (int j = 0; j < 8; ++j) {
        _Float16 h = (_Float16)v[j];
        hi[j] = h;
        lo[j] = (_Float16)(v[j] - (float)h);
    }
}

#define TILE3(C, A0H, A0L, A1H, A1L, PH, PL, T) do {                          \
        f16x8 b0h = *(const f16x8*)((PH) + (((T) * 2 + 0) * 64 + lane) * 8);  \
        f16x8 b0l = *(const f16x8*)((PL) + (((T) * 2 + 0) * 64 + lane) * 8);  \
        f16x8 b1h = *(const f16x8*)((PH) + (((T) * 2 + 1) * 64 + lane) * 8);  \
        f16x8 b1l = *(const f16x8*)((PL) + (((T) * 2 + 1) * 64 + lane) * 8);  \
        C = __builtin_amdgcn_mfma_f32_16x16x32_f16(A0H, b0h, C, 0, 0, 0);     \
        C = __builtin_amdgcn_mfma_f32_16x16x32_f16(A0L, b0h, C, 0, 0, 0);     \
        C = __builtin_amdgcn_mfma_f32_16x16x32_f16(A0H, b0l, C, 0, 0, 0);     \
        C = __builtin_amdgcn_mfma_f32_16x16x32_f16(A1H, b1h, C, 0, 0, 0);     \
        C = __builtin_amdgcn_mfma_f32_16x16x32_f16(A1L, b1h, C, 0, 0, 0);     \
        C = __builtin_amdgcn_mfma_f32_16x16x32_f16(A1H, b1l, C, 0, 0, 0);     \
    } while (0)

// ---------- conv1 node MLP via split-fp16 MFMA ----------
__global__ void node1_kernel(const float* __restrict__ xs,
                             const __half* __restrict__ pk1Ah, const __half* __restrict__ pk1Al,
                             const float* __restrict__ b1a,
                             const __half* __restrict__ pk1Bh, const __half* __restrict__ pk1Bl,
                             const float* __restrict__ b1b,
                             __half* __restrict__ h1lo,
                             __half* __restrict__ h1hi) {
    __shared__ float hbuf[4][16][68];
    int wv = threadIdx.x >> 6;
    int lane = threadIdx.x & 63;
    int gwave = blockIdx.x * 4 + wv;
    bool active = gwave < (N_NODES / 16);
    int base = active ? gwave * 16 : 0;
    int m = lane & 15, q = lane >> 4;
    const _Float16* pAh = (const _Float16*)pk1Ah;
    const _Float16* pAl = (const _Float16*)pk1Al;
    const _Float16* pBh = (const _Float16*)pk1Bh;
    const _Float16* pBl = (const _Float16*)pk1Bl;

    f16x8 ah, al;
    split8(xs + (size_t)(base + m) * 32 + q * 8, ah, al);
#pragma unroll
    for (int t = 0; t < 4; ++t) {
        f32x4 c = {0.f, 0.f, 0.f, 0.f};
        f16x8 bh = *(const f16x8*)(pAh + (t * 64 + lane) * 8);
        f16x8 bl = *(const f16x8*)(pAl + (t * 64 + lane) * 8);
        c = __builtin_amdgcn_mfma_f32_16x16x32_f16(ah, bh, c, 0, 0, 0);
        c = __builtin_amdgcn_mfma_f32_16x16x32_f16(al, bh, c, 0, 0, 0);
        c = __builtin_amdgcn_mfma_f32_16x16x32_f16(ah, bl, c, 0, 0, 0);
        float bias = b1a[t * 16 + m];
#pragma unroll
        for (int r = 0; r < 4; ++r)
            hbuf[wv][q * 4 + r][t * 16 + m] = fmaxf(c[r] + bias, 0.f);
    }
    __syncthreads();
    f16x8 a0h, a0l, a1h, a1l;
    split8(&hbuf[wv][m][q * 8], a0h, a0l);
    split8(&hbuf[wv][m][32 + q * 8], a1h, a1l);
    float tmp[4][4];
#pragma unroll
    for (int t = 0; t < 4; ++t) {
        f32x4 c = {0.f, 0.f, 0.f, 0.f};
        TILE3(c, a0h, a0l, a1h, a1l, pBh, pBl, t);
        float bias = b1b[t * 16 + m];
#pragma unroll
        for (int r = 0; r < 4; ++r)
            tmp[t][r] = fmaxf(c[r] + bias, 0.f);
    }
    __syncthreads();
#pragma unroll
    for (int t = 0; t < 4; ++t)
#pragma unroll
        for (int r = 0; r < 4; ++r)
            hbuf[wv][q * 4 + r][t * 16 + m] = tmp[t][r];
    __syncthreads();
    if (active) {
        int nn = lane >> 2, part = lane & 3;
        f16x8 vlo, vhi;
        const float* rlo = &hbuf[wv][nn][part * 8];
        const float* rhi = &hbuf[wv][nn][32 + part * 8];
#pragma unroll
        for (int j = 0; j < 8; ++j) {
            vlo[j] = (_Float16)rlo[j];
            vhi[j] = (_Float16)rhi[j];
        }
        *(f16x8*)(h1lo + (size_t)(base + nn) * 32 + part * 8) = vlo;
        *(f16x8*)(h1hi + (size_t)(base + nn) * 32 + part * 8) = vhi;
    }
}

// ---------- node2 via split-fp16 MFMA; writes pi + fused segmented te reduce ----------
__global__ void node2_kernel(const float* __restrict__ htot,
                             const __half* __restrict__ pkAh, const __half* __restrict__ pkAl,
                             const float* __restrict__ b2a,
                             const __half* __restrict__ pkBh, const __half* __restrict__ pkBl,
                             const float* __restrict__ b2b,
                             const __half* __restrict__ pkRh, const __half* __restrict__ pkRl,
                             const float* __restrict__ br1,
                             const float* __restrict__ wr2,
                             const float* __restrict__ br2,
                             const int* __restrict__ term,
                             const float* __restrict__ ccost,
                             const int* __restrict__ batch,
                             float* __restrict__ pi,
                             float* __restrict__ te) {
    __shared__ float hbuf[4][16][68];
    __shared__ float pcl[64];
    int wv = threadIdx.x >> 6;
    int lane = threadIdx.x & 63;
    int tid = threadIdx.x;
    if (tid < 64) pcl[tid] = 0.f;
    int gwave = blockIdx.x * 4 + wv;
    bool active = gwave < (N_NODES / 16);
    int base = active ? gwave * 16 : 0;
    int m = lane & 15, q = lane >> 4;
    const _Float16* pAh = (const _Float16*)pkAh;
    const _Float16* pAl = (const _Float16*)pkAl;
    const _Float16* pBh = (const _Float16*)pkBh;
    const _Float16* pBl = (const _Float16*)pkBl;
    const _Float16* pRh = (const _Float16*)pkRh;
    const _Float16* pRl = (const _Float16*)pkRl;

    f16x8 a0h, a0l, a1h, a1l;
    {
        const float* hrow = htot + (size_t)(base + m) * 64;
        split8(hrow + q * 8, a0h, a0l);
        split8(hrow + 32 + q * 8, a1h, a1l);
    }
#pragma unroll
    for (int t = 0; t < 4; ++t) {
        f32x4 c = {0.f, 0.f, 0.f, 0.f};
        TILE3(c, a0h, a0l, a1h, a1l, pAh, pAl, t);
        float bias = b2a[t * 16 + m];
#pragma unroll
        for (int r = 0; r < 4; ++r)
            hbuf[wv][q * 4 + r][t * 16 + m] = fmaxf(c[r] + bias, 0.f);
    }
    __syncthreads();
    split8(&hbuf[wv][m][q * 8], a0h, a0l);
    split8(&hbuf[wv][m][32 + q * 8], a1h, a1l);
    float tmp[4][4];
#pragma unroll
    for (int t = 0; t < 4; ++t) {
        f32x4 c = {0.f, 0.f, 0.f, 0.f};
        TILE3(c, a0h, a0l, a1h, a1l, pBh, pBl, t);
        float bias = b2b[t * 16 + m];
#pragma unroll
        for (int r = 0; r < 4; ++r)
            tmp[t][r] = fmaxf(c[r] + bias, 0.f);
    }
    __syncthreads();
#pragma unroll
    for (int t = 0; t < 4; ++t)
#pragma unroll
        for (int r = 0; r < 4; ++r)
            hbuf[wv][q * 4 + r][t * 16 + m] = tmp[t][r];
    __syncthreads();
    split8(&hbuf[wv][m][q * 8], a0h, a0l);
    split8(&hbuf[wv][m][32 + q * 8], a1h, a1l);
    float partial[4] = {0.f, 0.f, 0.f, 0.f};
#pragma unroll
    for (int t = 0; t < 2; ++t) {
        f32x4 c = {0.f, 0.f, 0.f, 0.f};
        TILE3(c, a0h, a0l, a1h, a1l, pRh, pRl, t);
        float bias = br1[t * 16 + m];
        float wv2 = wr2[t * 16 + m];
#pragma unroll
        for (int r = 0; r < 4; ++r)
            partial[r] += fmaxf(c[r] + bias, 0.f) * wv2;
    }
#pragma unroll
    for (int off = 1; off < 16; off <<= 1) {
        partial[0] += __shfl_xor(partial[0], off, 64);
        partial[1] += __shfl_xor(partial[1], off, 64);
        partial[2] += __shfl_xor(partial[2], off, 64);
        partial[3] += __shfl_xor(partial[3], off, 64);
    }
    if (active && m == 0) {
#pragma unroll
        for (int r = 0; r < 4; ++r) {
            int n = base + q * 4 + r;
            float z = partial[r] + br2[0];
            float sig = 1.f / (1.f + expf(-z));
            float p = sig * (1.f - (float)term[n]);
            pi[n] = p;
            pcl[wv * 16 + q * 4 + r] = p * ccost[n];
        }
    }
    __syncthreads();
    // segmented reduce over sorted batch: few graphs per 64-node block
    if (tid < 64) {
        int n0 = blockIdx.x * 64 + tid;
        if (n0 < N_NODES) {
            int gb = batch[n0];
            bool head = (tid == 0) || (batch[n0 - 1] != gb);
            if (head) {
                float s = 0.f;
                for (int k = tid; k < 64; ++k) {
                    int nk = blockIdx.x * 64 + k;
                    if (nk >= N_NODES || batch[nk] != gb) break;
                    s += pcl[k];
                }
                atomicAdd(&te[gb], s);
            }
        }
    }
}

__global__ void final_kernel(const float* __restrict__ pi,
                             const int* __restrict__ batch,
                             const float* __restrict__ Btot,
                             const float* __restrict__ te,
                             float* __restrict__ out) {
    int n = blockIdx.x * blockDim.x + threadIdx.x;
    if (n >= N_NODES) return;
    int b = batch[n];
    float ratio = fminf(Btot[b] / (te[b] + 1e-12f), 1.f);
    out[n] = pi[n] * ratio;
}

extern "C" void kernel_launch(void* const* d_in, const int* in_sizes, int n_in,
                              void* d_out, int out_size, void* d_ws, size_t ws_size,
                              hipStream_t stream) {
    const float* x     = (const float*)d_in[0];
    const int*   ei    = (const int*)d_in[1];
    const float* ea    = (const float*)d_in[2];
    const int*   batch = (const int*)d_in[3];
    const float* Btot  = (const float*)d_in[4];
    const int*   term  = (const int*)d_in[5];
    const float* ccost = (const float*)d_in[6];
    const float* e1w   = (const float*)d_in[7];
    const float* e1b   = (const float*)d_in[8];
    const float* w1a   = (const float*)d_in[9];
    const float* b1a   = (const float*)d_in[10];
    const float* w1b   = (const float*)d_in[11];
    const float* b1b   = (const float*)d_in[12];
    const float* e2w   = (const float*)d_in[13];
    const float* e2b   = (const float*)d_in[14];
    const float* w2a   = (const float*)d_in[15];
    const float* b2a   = (const float*)d_in[16];
    const float* w2b   = (const float*)d_in[17];
    const float* b2b   = (const float*)d_in[18];
    const float* wr1   = (const float*)d_in[19];
    const float* br1   = (const float*)d_in[20];
    const float* wr2   = (const float*)d_in[21];
    const float* br2   = (const float*)d_in[22];

    char* p = (char*)d_ws;
    int*      bnext  = (int*)p;      p += sizeof(int)      * 256;       // zeroed
    float*    te     = (float*)p;    p += sizeof(float)    * N_GRAPHS;  // zeroed
    p = (char*)(((size_t)p + 15) & ~(size_t)15);
    uint2*    ebuk   = (uint2*)p;    p += sizeof(uint2)    * (size_t)N_BUCKETS * FINE_CAP;
    __half*   h1lo   = (__half*)p;   p += sizeof(__half)   * (size_t)N_NODES * 32;
    __half*   h1hi   = (__half*)p;   p += sizeof(__half)   * (size_t)N_NODES * 32;
    float*    htot   = (float*)p;    p += sizeof(float)    * (size_t)N_NODES * 64;
    float*    xs     = (float*)p;    p += sizeof(float)    * (size_t)N_NODES * 32;
    float*    pi     = (float*)p;    p += sizeof(float)    * N_NODES;
    __half*   pk1Ah  = (__half*)p;   p += sizeof(__half)   * 2048;
    __half*   pk1Al  = (__half*)p;   p += sizeof(__half)   * 2048;
    __half*   pk1Bh  = (__half*)p;   p += sizeof(__half)   * 4096;
    __half*   pk1Bl  = (__half*)p;   p += sizeof(__half)   * 4096;
    __half*   pkAh   = (__half*)p;   p += sizeof(__half)   * 4096;
    __half*   pkAl   = (__half*)p;   p += sizeof(__half)   * 4096;
    __half*   pkBh   = (__half*)p;   p += sizeof(__half)   * 4096;
    __half*   pkBl   = (__half*)p;   p += sizeof(__half)   * 4096;
    __half*   pkRh   = (__half*)p;   p += sizeof(__half)   * 2048;
    __half*   pkRl   = (__half*)p;   p += sizeof(__half)   * 2048;
    float*    out    = (float*)d_out;

    hipMemsetAsync(d_ws, 0, sizeof(int) * 256 + sizeof(float) * N_GRAPHS, stream);

    bucket_scatter<<<1 + N_SBLK, 256, 0, stream>>>(ei, ea, bnext, ebuk,
                                                   w1a, w1b, w2a, w2b, wr1,
                                                   pk1Ah, pk1Al, pk1Bh, pk1Bl,
                                                   pkAh, pkAl, pkBh, pkBl, pkRh, pkRl);
    aggbucket1<<<N_BUCKETS, 1024, 0, stream>>>(x, bnext, ebuk, e1w, e1b, xs);
    node1_kernel<<<(N_NODES / 16 + 3) / 4, 256, 0, stream>>>(xs, pk1Ah, pk1Al, b1a,
                                                             pk1Bh, pk1Bl, b1b,
                                                             h1lo, h1hi);
    aggbucket2<<<N_BUCKETS, 1024, 0, stream>>>(h1lo, bnext, ebuk, e2w, e2b, htot, 0);
    aggbucket2<<<N_BUCKETS, 1024, 0, stream>>>(h1hi, bnext, ebuk, e2w + 32, e2b + 32,
                                               htot, 32);
    node2_kernel<<<(N_NODES / 16 + 3) / 4, 256, 0, stream>>>(htot,
                                                             pkAh, pkAl, b2a,
                                                             pkBh, pkBl, b2b,
                                                             pkRh, pkRl, br1,
                                                             wr2, br2, term,
                                                             ccost, batch, pi, te);
    final_kernel<<<(N_NODES + 255) / 256, 256, 0, stream>>>(pi, batch, Btot, te, out);
}

// Round 17
// 270.088 us; speedup vs baseline: 3.5573x; 3.5573x over previous
//
#include <hip/hip_runtime.h>
#include <hip/hip_fp16.h>
#include <math.h>

#define N_NODES 50000
#define N_EDGES 1600000
#define N_GRAPHS 512
#define F_IN 9
#define H 64
#define N_BUCKETS ((N_NODES + 255) >> 8)     // 196
#define EPB 8192
#define N_SBLK ((N_EDGES + EPB - 1) / EPB)   // 196
#define FINE_CAP 10240                        // mean 8192, sd ~90 -> +22 sd

typedef _Float16 f16x8 __attribute__((ext_vector_type(8)));
typedef float f32x4 __attribute__((ext_vector_type(4)));

__device__ __forceinline__ void pack_weights_body(
        const float* __restrict__ w1a, const float* __restrict__ w1b,
        const float* __restrict__ w2a, const float* __restrict__ w2b,
        const float* __restrict__ wr1,
        __half* __restrict__ pk1Ah, __half* __restrict__ pk1Al,
        __half* __restrict__ pk1Bh, __half* __restrict__ pk1Bl,
        __half* __restrict__ pkAh, __half* __restrict__ pkAl,
        __half* __restrict__ pkBh, __half* __restrict__ pkBl,
        __half* __restrict__ pkRh, __half* __restrict__ pkRl) {
    int t = threadIdx.x;
    for (int i = t; i < 2048; i += 256) {      // w1a: [64][9], K=32 zero-pad
        int j = i & 7, l = (i >> 3) & 63, tt = i >> 9;
        int q = l >> 4, n = l & 15;
        int k = q * 8 + j;
        float v = (k < F_IN) ? w1a[(tt * 16 + n) * F_IN + k] : 0.f;
        __half h = __float2half(v);
        pk1Ah[i] = h; pk1Al[i] = __float2half(v - __half2float(h));
    }
    for (int i = t; i < 4096; i += 256) {
        int j = i & 7, l = (i >> 3) & 63, c = (i >> 9) & 1, tt = i >> 10;
        int q = l >> 4, n = l & 15;
        int src = (tt * 16 + n) * H + c * 32 + q * 8 + j;
        float v1 = w1b[src], wa = w2a[src], wb = w2b[src];
        __half h1 = __float2half(v1), ah = __float2half(wa), bh = __float2half(wb);
        pk1Bh[i] = h1; pk1Bl[i] = __float2half(v1 - __half2float(h1));
        pkAh[i] = ah; pkAl[i] = __float2half(wa - __half2float(ah));
        pkBh[i] = bh; pkBl[i] = __float2half(wb - __half2float(bh));
    }
    for (int i = t; i < 2048; i += 256) {
        int j = i & 7, l = (i >> 3) & 63, c = (i >> 9) & 1, tt = i >> 10;
        int q = l >> 4, n = l & 15;
        float wr = wr1[(tt * 16 + n) * H + c * 32 + q * 8 + j];
        __half rh = __float2half(wr);
        pkRh[i] = rh; pkRl[i] = __float2half(wr - __half2float(rh));
    }
}

// ---------- bucket scatter (fixed-capacity buckets); block 0 packs weights ----------
__global__ void bucket_scatter(const int* __restrict__ ei,
                               const float* __restrict__ ea,
                               int* __restrict__ bnext,
                               uint2* __restrict__ ebuk,
                               const float* __restrict__ w1a,
                               const float* __restrict__ w1b,
                               const float* __restrict__ w2a,
                               const float* __restrict__ w2b,
                               const float* __restrict__ wr1,
                               __half* pk1Ah, __half* pk1Al,
                               __half* pk1Bh, __half* pk1Bl,
                               __half* pkAh, __half* pkAl,
                               __half* pkBh, __half* pkBl,
                               __half* pkRh, __half* pkRl) {
    if (blockIdx.x == 0) {
        pack_weights_body(w1a, w1b, w2a, w2b, wr1, pk1Ah, pk1Al, pk1Bh, pk1Bl,
                          pkAh, pkAl, pkBh, pkBl, pkRh, pkRl);
        return;
    }
    __shared__ int cnt[N_BUCKETS];
    __shared__ int gbase[N_BUCKETS];
    for (int i = threadIdx.x; i < N_BUCKETS; i += 256) cnt[i] = 0;
    __syncthreads();
    int base = (blockIdx.x - 1) * EPB;
    int rk[32];
#pragma unroll
    for (int j = 0; j < 32; ++j) {
        int e = base + j * 256 + threadIdx.x;
        rk[j] = -1;
        if (e < N_EDGES) {
            int d = ei[N_EDGES + e];
            int b = d >> 8;
            int r = atomicAdd(&cnt[b], 1);
            rk[j] = (b << 21) | ((d & 255) << 13) | r;
        }
    }
    __syncthreads();
    for (int i = threadIdx.x; i < N_BUCKETS; i += 256)
        gbase[i] = cnt[i] ? atomicAdd(&bnext[i], cnt[i]) : 0;
    __syncthreads();
#pragma unroll
    for (int j = 0; j < 32; ++j) {
        if (rk[j] < 0) continue;
        int e = base + j * 256 + threadIdx.x;
        int b = rk[j] >> 21, dl = (rk[j] >> 13) & 255, r = rk[j] & 8191;
        int slot = gbase[b] + r;
        if (slot >= FINE_CAP) continue;
        unsigned pay = ((unsigned)ei[e] << 16) |
                       (unsigned)__half_as_ushort(__float2half(ea[e]));
        ebuk[(size_t)b * FINE_CAP + slot] = make_uint2(pay, (unsigned)dl);
    }
}

// ---------- per-bucket fine sort -> node CSR + node-sorted ep4 ----------
__global__ void __launch_bounds__(256)
bucket_fine(const uint2* __restrict__ ebuk,
            const int* __restrict__ bnext,
            unsigned* __restrict__ ep4,
            int* __restrict__ starts, int* __restrict__ deg) {
    __shared__ unsigned sorted[FINE_CAP];
    __shared__ int cntN[256], offN[256], nxtN[256];
    __shared__ int wsum[4];
    int b = blockIdx.x;
    int base = b * FINE_CAP;
    int count = bnext[b];
    if (count > FINE_CAP) count = FINE_CAP;
    int tid = threadIdx.x;
    cntN[tid] = 0;
    __syncthreads();
    for (int i = tid; i < count; i += 256)
        atomicAdd(&cntN[ebuk[base + i].y], 1);
    __syncthreads();
    int lane = tid & 63, wid = tid >> 6;
    int v = cntN[tid], incl = v;
#pragma unroll
    for (int off = 1; off < 64; off <<= 1) {
        int t = __shfl_up(incl, off, 64);
        if (lane >= off) incl += t;
    }
    if (lane == 63) wsum[wid] = incl;
    __syncthreads();
    int woff = 0;
    for (int w = 0; w < wid; ++w) woff += wsum[w];
    int excl = woff + incl - v;
    offN[tid] = excl;
    nxtN[tid] = 0;
    int n = (b << 8) + tid;
    if (n < N_NODES) { starts[n] = base + excl; deg[n] = v; }
    __syncthreads();
    for (int i = tid; i < count; i += 256) {
        uint2 e = ebuk[base + i];
        int r = atomicAdd(&nxtN[e.y], 1);
        sorted[offN[e.y] + r] = e.x;
    }
    __syncthreads();
    for (int i = tid; i < count; i += 256)
        ep4[base + i] = sorted[i];
}

#define UNPACK_ATTR(P) __half2float(__ushort_as_half((unsigned short)((P) & 0xffffu)))

// ---------- conv1 aggregation: writes xs[n][32] = (x + agg, zero-padded) ----------
__global__ void agg1_kernel(const float* __restrict__ x,
                            const int* __restrict__ starts,
                            const int* __restrict__ deg,
                            const unsigned* __restrict__ ep4,
                            const float* __restrict__ e1w,
                            const float* __restrict__ e1b,
                            float* __restrict__ xs) {
    int n = blockIdx.x * (blockDim.x >> 6) + (threadIdx.x >> 6);
    int lane = threadIdx.x & 63;
    if (n >= N_NODES) return;
    int slot = lane >> 4;
    int f = lane & 15;
    int s0 = starts[n], dg = deg[n];
    bool act = f < F_IN;
    float wf = act ? e1w[f] : 0.f;
    float bf = act ? e1b[f] : 0.f;
    float acc = 0.f;
    int j = slot;
    for (; j + 12 < dg; j += 16) {
        unsigned pa = ep4[s0 + j];
        unsigned pb = ep4[s0 + j + 4];
        unsigned pc = ep4[s0 + j + 8];
        unsigned pd = ep4[s0 + j + 12];
        float xa_ = act ? x[(pa >> 16) * F_IN + f] : 0.f;
        float xb_ = act ? x[(pb >> 16) * F_IN + f] : 0.f;
        float xc_ = act ? x[(pc >> 16) * F_IN + f] : 0.f;
        float xd_ = act ? x[(pd >> 16) * F_IN + f] : 0.f;
        if (act) {
            acc += fmaxf(xa_ + UNPACK_ATTR(pa) * wf + bf, 0.f)
                 + fmaxf(xb_ + UNPACK_ATTR(pb) * wf + bf, 0.f)
                 + fmaxf(xc_ + UNPACK_ATTR(pc) * wf + bf, 0.f)
                 + fmaxf(xd_ + UNPACK_ATTR(pd) * wf + bf, 0.f);
        }
    }
    for (; j < dg; j += 4) {
        unsigned p = ep4[s0 + j];
        float xv = act ? x[(p >> 16) * F_IN + f] : 0.f;
        float m = xv + UNPACK_ATTR(p) * wf + bf;
        acc += act ? fmaxf(m, 0.f) : 0.f;
    }
    acc += __shfl_xor(acc, 16, 64);
    acc += __shfl_xor(acc, 32, 64);
    if (lane < 32)
        xs[n * 32 + lane] = (lane < F_IN) ? x[n * F_IN + lane] + acc : 0.f;
}

__device__ __forceinline__ void split8(const float* __restrict__ v,
                                       f16x8& hi, f16x8& lo) {
#pragma unroll
    for (int j = 0; j < 8; ++j) {
        _Float16 h = (_Float16)v[j];
        hi[j] = h;
        lo[j] = (_Float16)(v[j] - (float)h);
    }
}

#define TILE3(C, A0H, A0L, A1H, A1L, PH, PL, T) do {                          \
        f16x8 b0h = *(const f16x8*)((PH) + (((T) * 2 + 0) * 64 + lane) * 8);  \
        f16x8 b0l = *(const f16x8*)((PL) + (((T) * 2 + 0) * 64 + lane) * 8);  \
        f16x8 b1h = *(const f16x8*)((PH) + (((T) * 2 + 1) * 64 + lane) * 8);  \
        f16x8 b1l = *(const f16x8*)((PL) + (((T) * 2 + 1) * 64 + lane) * 8);  \
        C = __builtin_amdgcn_mfma_f32_16x16x32_f16(A0H, b0h, C, 0, 0, 0);     \
        C = __builtin_amdgcn_mfma_f32_16x16x32_f16(A0L, b0h, C, 0, 0, 0);     \
        C = __builtin_amdgcn_mfma_f32_16x16x32_f16(A0H, b0l, C, 0, 0, 0);     \
        C = __builtin_amdgcn_mfma_f32_16x16x32_f16(A1H, b1h, C, 0, 0, 0);     \
        C = __builtin_amdgcn_mfma_f32_16x16x32_f16(A1L, b1h, C, 0, 0, 0);     \
        C = __builtin_amdgcn_mfma_f32_16x16x32_f16(A1H, b1l, C, 0, 0, 0);     \
    } while (0)

// ---------- conv1 node MLP via split-fp16 MFMA ----------
__global__ void node1_kernel(const float* __restrict__ xs,
                             const __half* __restrict__ pk1Ah, const __half* __restrict__ pk1Al,
                             const float* __restrict__ b1a,
                             const __half* __restrict__ pk1Bh, const __half* __restrict__ pk1Bl,
                             const float* __restrict__ b1b,
                             __half* __restrict__ h1lo,
                             __half* __restrict__ h1hi) {
    __shared__ float hbuf[4][16][68];
    int wv = threadIdx.x >> 6;
    int lane = threadIdx.x & 63;
    int gwave = blockIdx.x * 4 + wv;
    bool active = gwave < (N_NODES / 16);
    int base = active ? gwave * 16 : 0;
    int m = lane & 15, q = lane >> 4;
    const _Float16* pAh = (const _Float16*)pk1Ah;
    const _Float16* pAl = (const _Float16*)pk1Al;
    const _Float16* pBh = (const _Float16*)pk1Bh;
    const _Float16* pBl = (const _Float16*)pk1Bl;

    f16x8 ah, al;
    split8(xs + (size_t)(base + m) * 32 + q * 8, ah, al);
#pragma unroll
    for (int t = 0; t < 4; ++t) {
        f32x4 c = {0.f, 0.f, 0.f, 0.f};
        f16x8 bh = *(const f16x8*)(pAh + (t * 64 + lane) * 8);
        f16x8 bl = *(const f16x8*)(pAl + (t * 64 + lane) * 8);
        c = __builtin_amdgcn_mfma_f32_16x16x32_f16(ah, bh, c, 0, 0, 0);
        c = __builtin_amdgcn_mfma_f32_16x16x32_f16(al, bh, c, 0, 0, 0);
        c = __builtin_amdgcn_mfma_f32_16x16x32_f16(ah, bl, c, 0, 0, 0);
        float bias = b1a[t * 16 + m];
#pragma unroll
        for (int r = 0; r < 4; ++r)
            hbuf[wv][q * 4 + r][t * 16 + m] = fmaxf(c[r] + bias, 0.f);
    }
    __syncthreads();
    f16x8 a0h, a0l, a1h, a1l;
    split8(&hbuf[wv][m][q * 8], a0h, a0l);
    split8(&hbuf[wv][m][32 + q * 8], a1h, a1l);
    float tmp[4][4];
#pragma unroll
    for (int t = 0; t < 4; ++t) {
        f32x4 c = {0.f, 0.f, 0.f, 0.f};
        TILE3(c, a0h, a0l, a1h, a1l, pBh, pBl, t);
        float bias = b1b[t * 16 + m];
#pragma unroll
        for (int r = 0; r < 4; ++r)
            tmp[t][r] = fmaxf(c[r] + bias, 0.f);
    }
    __syncthreads();
#pragma unroll
    for (int t = 0; t < 4; ++t)
#pragma unroll
        for (int r = 0; r < 4; ++r)
            hbuf[wv][q * 4 + r][t * 16 + m] = tmp[t][r];
    __syncthreads();
    if (active) {
        int nn = lane >> 2, part = lane & 3;
        f16x8 vlo, vhi;
        const float* rlo = &hbuf[wv][nn][part * 8];
        const float* rhi = &hbuf[wv][nn][32 + part * 8];
#pragma unroll
        for (int j = 0; j < 8; ++j) {
            vlo[j] = (_Float16)rlo[j];
            vhi[j] = (_Float16)rhi[j];
        }
        *(f16x8*)(h1lo + (size_t)(base + nn) * 32 + part * 8) = vlo;
        *(f16x8*)(h1hi + (size_t)(base + nn) * 32 + part * 8) = vhi;
    }
}

// ---------- conv2 aggregation phase (L2-resident 3.2MB half) ----------
__global__ void aggphase_kernel(const __half* __restrict__ harr,
                                const int* __restrict__ starts,
                                const int* __restrict__ deg,
                                const unsigned* __restrict__ ep4,
                                const float* __restrict__ ew,
                                const float* __restrict__ eb,
                                float* __restrict__ htot, int foff) {
    int n = blockIdx.x * (blockDim.x >> 6) + (threadIdx.x >> 6);
    int lane = threadIdx.x & 63;
    if (n >= N_NODES) return;
    int half = lane >> 5;
    int fh = lane & 31;
    int s0 = starts[n], dg = deg[n];
    const unsigned* ep = ep4 + s0;
    float wf = ew[fh], bf = eb[fh];
    float acc = 0.f;
    int j = 0;
#define EDGE1(P, V) acc += fmaxf((V) + UNPACK_ATTR(P) * wf + bf, 0.f)
    for (; j + 16 <= dg; j += 16) {
        unsigned p0 = ep[j +  0 + half], p1 = ep[j +  2 + half];
        unsigned p2 = ep[j +  4 + half], p3 = ep[j +  6 + half];
        unsigned p4 = ep[j +  8 + half], p5 = ep[j + 10 + half];
        unsigned p6 = ep[j + 12 + half], p7 = ep[j + 14 + half];
        float v0 = __half2float(harr[(p0 >> 16) * 32 + fh]);
        float v1 = __half2float(harr[(p1 >> 16) * 32 + fh]);
        float v2 = __half2float(harr[(p2 >> 16) * 32 + fh]);
        float v3 = __half2float(harr[(p3 >> 16) * 32 + fh]);
        float v4 = __half2float(harr[(p4 >> 16) * 32 + fh]);
        float v5 = __half2float(harr[(p5 >> 16) * 32 + fh]);
        float v6 = __half2float(harr[(p6 >> 16) * 32 + fh]);
        float v7 = __half2float(harr[(p7 >> 16) * 32 + fh]);
        EDGE1(p0, v0); EDGE1(p1, v1); EDGE1(p2, v2); EDGE1(p3, v3);
        EDGE1(p4, v4); EDGE1(p5, v5); EDGE1(p6, v6); EDGE1(p7, v7);
    }
    for (; j + 2 <= dg; j += 2) {
        unsigned p = ep[j + half];
        float v = __half2float(harr[(p >> 16) * 32 + fh]);
        EDGE1(p, v);
    }
    if (j < dg && half == 0) {
        unsigned p = ep[j];
        float v = __half2float(harr[(p >> 16) * 32 + fh]);
        EDGE1(p, v);
    }
#undef EDGE1
    acc += __shfl_xor(acc, 32, 64);
    if (half == 0) {
        float h1v = __half2float(harr[n * 32 + fh]);
        htot[(size_t)n * 64 + foff + fh] = h1v + acc;
    }
}

// ---------- node2 via split-fp16 MFMA; writes pi + fused segmented te reduce ----------
__global__ void node2_kernel(const float* __restrict__ htot,
                             const __half* __restrict__ pkAh, const __half* __restrict__ pkAl,
                             const float* __restrict__ b2a,
                             const __half* __restrict__ pkBh, const __half* __restrict__ pkBl,
                             const float* __restrict__ b2b,
                             const __half* __restrict__ pkRh, const __half* __restrict__ pkRl,
                             const float* __restrict__ br1,
                             const float* __restrict__ wr2,
                             const float* __restrict__ br2,
                             const int* __restrict__ term,
                             const float* __restrict__ ccost,
                             const int* __restrict__ batch,
                             float* __restrict__ pi,
                             float* __restrict__ te) {
    __shared__ float hbuf[4][16][68];
    __shared__ float pcl[64];
    int wv = threadIdx.x >> 6;
    int lane = threadIdx.x & 63;
    int tid = threadIdx.x;
    if (tid < 64) pcl[tid] = 0.f;
    int gwave = blockIdx.x * 4 + wv;
    bool active = gwave < (N_NODES / 16);
    int base = active ? gwave * 16 : 0;
    int m = lane & 15, q = lane >> 4;
    const _Float16* pAh = (const _Float16*)pkAh;
    const _Float16* pAl = (const _Float16*)pkAl;
    const _Float16* pBh = (const _Float16*)pkBh;
    const _Float16* pBl = (const _Float16*)pkBl;
    const _Float16* pRh = (const _Float16*)pkRh;
    const _Float16* pRl = (const _Float16*)pkRl;

    f16x8 a0h, a0l, a1h, a1l;
    {
        const float* hrow = htot + (size_t)(base + m) * 64;
        split8(hrow + q * 8, a0h, a0l);
        split8(hrow + 32 + q * 8, a1h, a1l);
    }
#pragma unroll
    for (int t = 0; t < 4; ++t) {
        f32x4 c = {0.f, 0.f, 0.f, 0.f};
        TILE3(c, a0h, a0l, a1h, a1l, pAh, pAl, t);
        float bias = b2a[t * 16 + m];
#pragma unroll
        for (int r = 0; r < 4; ++r)
            hbuf[wv][q * 4 + r][t * 16 + m] = fmaxf(c[r] + bias, 0.f);
    }
    __syncthreads();
    split8(&hbuf[wv][m][q * 8], a0h, a0l);
    split8(&hbuf[wv][m][32 + q * 8], a1h, a1l);
    float tmp[4][4];
#pragma unroll
    for (int t = 0; t < 4; ++t) {
        f32x4 c = {0.f, 0.f, 0.f, 0.f};
        TILE3(c, a0h, a0l, a1h, a1l, pBh, pBl, t);
        float bias = b2b[t * 16 + m];
#pragma unroll
        for (int r = 0; r < 4; ++r)
            tmp[t][r] = fmaxf(c[r] + bias, 0.f);
    }
    __syncthreads();
#pragma unroll
    for (int t = 0; t < 4; ++t)
#pragma unroll
        for (int r = 0; r < 4; ++r)
            hbuf[wv][q * 4 + r][t * 16 + m] = tmp[t][r];
    __syncthreads();
    split8(&hbuf[wv][m][q * 8], a0h, a0l);
    split8(&hbuf[wv][m][32 + q * 8], a1h, a1l);
    float partial[4] = {0.f, 0.f, 0.f, 0.f};
#pragma unroll
    for (int t = 0; t < 2; ++t) {
        f32x4 c = {0.f, 0.f, 0.f, 0.f};
        TILE3(c, a0h, a0l, a1h, a1l, pRh, pRl, t);
        float bias = br1[t * 16 + m];
        float wv2 = wr2[t * 16 + m];
#pragma unroll
        for (int r = 0; r < 4; ++r)
            partial[r] += fmaxf(c[r] + bias, 0.f) * wv2;
    }
#pragma unroll
    for (int off = 1; off < 16; off <<= 1) {
        partial[0] += __shfl_xor(partial[0], off, 64);
        partial[1] += __shfl_xor(partial[1], off, 64);
        partial[2] += __shfl_xor(partial[2], off, 64);
        partial[3] += __shfl_xor(partial[3], off, 64);
    }
    if (active && m == 0) {
#pragma unroll
        for (int r = 0; r < 4; ++r) {
            int n = base + q * 4 + r;
            float z = partial[r] + br2[0];
            float sig = 1.f / (1.f + expf(-z));
            float p = sig * (1.f - (float)term[n]);
            pi[n] = p;
            pcl[wv * 16 + q * 4 + r] = p * ccost[n];
        }
    }
    __syncthreads();
    // segmented reduce over sorted batch: few graphs per 64-node block
    if (tid < 64) {
        int n0 = blockIdx.x * 64 + tid;
        if (n0 < N_NODES) {
            int gb = batch[n0];
            bool head = (tid == 0) || (batch[n0 - 1] != gb);
            if (head) {
                float s = 0.f;
                for (int k = tid; k < 64; ++k) {
                    int nk = blockIdx.x * 64 + k;
                    if (nk >= N_NODES || batch[nk] != gb) break;
                    s += pcl[k];
                }
                atomicAdd(&te[gb], s);
            }
        }
    }
}

__global__ void final_kernel(const float* __restrict__ pi,
                             const int* __restrict__ batch,
                             const float* __restrict__ Btot,
                             const float* __restrict__ te,
                             float* __restrict__ out) {
    int n = blockIdx.x * blockDim.x + threadIdx.x;
    if (n >= N_NODES) return;
    int b = batch[n];
    float ratio = fminf(Btot[b] / (te[b] + 1e-12f), 1.f);
    out[n] = pi[n] * ratio;
}

extern "C" void kernel_launch(void* const* d_in, const int* in_sizes, int n_in,
                              void* d_out, int out_size, void* d_ws, size_t ws_size,
                              hipStream_t stream) {
    const float* x     = (const float*)d_in[0];
    const int*   ei    = (const int*)d_in[1];
    const float* ea    = (const float*)d_in[2];
    const int*   batch = (const int*)d_in[3];
    const float* Btot  = (const float*)d_in[4];
    const int*   term  = (const int*)d_in[5];
    const float* ccost = (const float*)d_in[6];
    const float* e1w   = (const float*)d_in[7];
    const float* e1b   = (const float*)d_in[8];
    const float* w1a   = (const float*)d_in[9];
    const float* b1a   = (const float*)d_in[10];
    const float* w1b   = (const float*)d_in[11];
    const float* b1b   = (const float*)d_in[12];
    const float* e2w   = (const float*)d_in[13];
    const float* e2b   = (const float*)d_in[14];
    const float* w2a   = (const float*)d_in[15];
    const float* b2a   = (const float*)d_in[16];
    const float* w2b   = (const float*)d_in[17];
    const float* b2b   = (const float*)d_in[18];
    const float* wr1   = (const float*)d_in[19];
    const float* br1   = (const float*)d_in[20];
    const float* wr2   = (const float*)d_in[21];
    const float* br2   = (const float*)d_in[22];

    char* p = (char*)d_ws;
    int*      bnext  = (int*)p;      p += sizeof(int)      * 256;       // zeroed
    float*    te     = (float*)p;    p += sizeof(float)    * N_GRAPHS;  // zeroed
    int*      starts = (int*)p;      p += sizeof(int)      * N_NODES;
    int*      deg    = (int*)p;      p += sizeof(int)      * N_NODES;
    p = (char*)(((size_t)p + 15) & ~(size_t)15);
    uint2*    ebuk   = (uint2*)p;    p += sizeof(uint2)    * (size_t)N_BUCKETS * FINE_CAP;
    unsigned* ep4    = (unsigned*)p; p += sizeof(unsigned) * (size_t)N_BUCKETS * FINE_CAP;
    __half*   h1lo   = (__half*)p;   p += sizeof(__half)   * (size_t)N_NODES * 32;
    __half*   h1hi   = (__half*)p;   p += sizeof(__half)   * (size_t)N_NODES * 32;
    float*    htot   = (float*)p;    p += sizeof(float)    * (size_t)N_NODES * 64;
    float*    xs     = (float*)p;    p += sizeof(float)    * (size_t)N_NODES * 32;
    float*    pi     = (float*)p;    p += sizeof(float)    * N_NODES;
    __half*   pk1Ah  = (__half*)p;   p += sizeof(__half)   * 2048;
    __half*   pk1Al  = (__half*)p;   p += sizeof(__half)   * 2048;
    __half*   pk1Bh  = (__half*)p;   p += sizeof(__half)   * 4096;
    __half*   pk1Bl  = (__half*)p;   p += sizeof(__half)   * 4096;
    __half*   pkAh   = (__half*)p;   p += sizeof(__half)   * 4096;
    __half*   pkAl   = (__half*)p;   p += sizeof(__half)   * 4096;
    __half*   pkBh   = (__half*)p;   p += sizeof(__half)   * 4096;
    __half*   pkBl   = (__half*)p;   p += sizeof(__half)   * 4096;
    __half*   pkRh   = (__half*)p;   p += sizeof(__half)   * 2048;
    __half*   pkRl   = (__half*)p;   p += sizeof(__half)   * 2048;
    float*    out    = (float*)d_out;

    hipMemsetAsync(d_ws, 0, sizeof(int) * 256 + sizeof(float) * N_GRAPHS, stream);

    bucket_scatter<<<1 + N_SBLK, 256, 0, stream>>>(ei, ea, bnext, ebuk,
                                                   w1a, w1b, w2a, w2b, wr1,
                                                   pk1Ah, pk1Al, pk1Bh, pk1Bl,
                                                   pkAh, pkAl, pkBh, pkBl, pkRh, pkRl);
    bucket_fine<<<N_BUCKETS, 256, 0, stream>>>(ebuk, bnext, ep4, starts, deg);
    agg1_kernel<<<(N_NODES + 3) / 4, 256, 0, stream>>>(x, starts, deg, ep4, e1w, e1b, xs);
    node1_kernel<<<(N_NODES / 16 + 3) / 4, 256, 0, stream>>>(xs, pk1Ah, pk1Al, b1a,
                                                             pk1Bh, pk1Bl, b1b,
                                                             h1lo, h1hi);
    aggphase_kernel<<<(N_NODES + 3) / 4, 256, 0, stream>>>(h1lo, starts, deg, ep4,
                                                           e2w, e2b, htot, 0);
    aggphase_kernel<<<(N_NODES + 3) / 4, 256, 0, stream>>>(h1hi, starts, deg, ep4,
                                                           e2w + 32, e2b + 32, htot, 32);
    node2_kernel<<<(N_NODES / 16 + 3) / 4, 256, 0, stream>>>(htot,
                                                             pkAh, pkAl, b2a,
                                                             pkBh, pkBl, b2b,
                                                             pkRh, pkRl, br1,
                                                             wr2, br2, term,
                                                             ccost, batch, pi, te);
    final_kernel<<<(N_NODES + 255) / 256, 256, 0, stream>>>(pi, batch, Btot, te, out);
}

// Round 18
// 258.732 us; speedup vs baseline: 3.7135x; 1.0439x over previous
//
#include <hip/hip_runtime.h>
#include <hip/hip_fp16.h>
#include <math.h>

#define N_NODES 50000
#define N_EDGES 1600000
#define N_GRAPHS 512
#define F_IN 9
#define H 64
#define N_BUCKETS ((N_NODES + 255) >> 8)     // 196
#define EPB 4096
#define N_SBLK ((N_EDGES + EPB - 1) / EPB)   // 391
#define FINE_CAP 10240                        // mean 8192, sd ~90 -> +22 sd

typedef _Float16 f16x8 __attribute__((ext_vector_type(8)));
typedef float f32x4 __attribute__((ext_vector_type(4)));

__device__ __forceinline__ void pack_weights_body(
        const float* __restrict__ w1a, const float* __restrict__ w1b,
        const float* __restrict__ w2a, const float* __restrict__ w2b,
        const float* __restrict__ wr1,
        __half* __restrict__ pk1Ah, __half* __restrict__ pk1Al,
        __half* __restrict__ pk1Bh, __half* __restrict__ pk1Bl,
        __half* __restrict__ pkAh, __half* __restrict__ pkAl,
        __half* __restrict__ pkBh, __half* __restrict__ pkBl,
        __half* __restrict__ pkRh, __half* __restrict__ pkRl) {
    int t = threadIdx.x;
    for (int i = t; i < 2048; i += 256) {      // w1a: [64][9], K=32 zero-pad
        int j = i & 7, l = (i >> 3) & 63, tt = i >> 9;
        int q = l >> 4, n = l & 15;
        int k = q * 8 + j;
        float v = (k < F_IN) ? w1a[(tt * 16 + n) * F_IN + k] : 0.f;
        __half h = __float2half(v);
        pk1Ah[i] = h; pk1Al[i] = __float2half(v - __half2float(h));
    }
    for (int i = t; i < 4096; i += 256) {
        int j = i & 7, l = (i >> 3) & 63, c = (i >> 9) & 1, tt = i >> 10;
        int q = l >> 4, n = l & 15;
        int src = (tt * 16 + n) * H + c * 32 + q * 8 + j;
        float v1 = w1b[src], wa = w2a[src], wb = w2b[src];
        __half h1 = __float2half(v1), ah = __float2half(wa), bh = __float2half(wb);
        pk1Bh[i] = h1; pk1Bl[i] = __float2half(v1 - __half2float(h1));
        pkAh[i] = ah; pkAl[i] = __float2half(wa - __half2float(ah));
        pkBh[i] = bh; pkBl[i] = __float2half(wb - __half2float(bh));
    }
    for (int i = t; i < 2048; i += 256) {
        int j = i & 7, l = (i >> 3) & 63, c = (i >> 9) & 1, tt = i >> 10;
        int q = l >> 4, n = l & 15;
        float wr = wr1[(tt * 16 + n) * H + c * 32 + q * 8 + j];
        __half rh = __float2half(wr);
        pkRh[i] = rh; pkRl[i] = __float2half(wr - __half2float(rh));
    }
}

// ---------- bucket scatter (fixed-capacity buckets); block 0 packs weights ----------
__global__ void bucket_scatter(const int* __restrict__ ei,
                               const float* __restrict__ ea,
                               int* __restrict__ bnext,
                               uint2* __restrict__ ebuk,
                               const float* __restrict__ w1a,
                               const float* __restrict__ w1b,
                               const float* __restrict__ w2a,
                               const float* __restrict__ w2b,
                               const float* __restrict__ wr1,
                               __half* pk1Ah, __half* pk1Al,
                               __half* pk1Bh, __half* pk1Bl,
                               __half* pkAh, __half* pkAl,
                               __half* pkBh, __half* pkBl,
                               __half* pkRh, __half* pkRl) {
    if (blockIdx.x == 0) {
        pack_weights_body(w1a, w1b, w2a, w2b, wr1, pk1Ah, pk1Al, pk1Bh, pk1Bl,
                          pkAh, pkAl, pkBh, pkBl, pkRh, pkRl);
        return;
    }
    __shared__ int cnt[N_BUCKETS];
    __shared__ int gbase[N_BUCKETS];
    for (int i = threadIdx.x; i < N_BUCKETS; i += 256) cnt[i] = 0;
    __syncthreads();
    int base = (blockIdx.x - 1) * EPB;
    int rk[16];
#pragma unroll
    for (int j = 0; j < 16; ++j) {
        int e = base + j * 256 + threadIdx.x;
        rk[j] = -1;
        if (e < N_EDGES) {
            int d = ei[N_EDGES + e];
            int b = d >> 8;
            int r = atomicAdd(&cnt[b], 1);
            rk[j] = (b << 21) | ((d & 255) << 13) | r;
        }
    }
    __syncthreads();
    for (int i = threadIdx.x; i < N_BUCKETS; i += 256)
        gbase[i] = cnt[i] ? atomicAdd(&bnext[i], cnt[i]) : 0;
    __syncthreads();
#pragma unroll
    for (int j = 0; j < 16; ++j) {
        if (rk[j] < 0) continue;
        int e = base + j * 256 + threadIdx.x;
        int b = rk[j] >> 21, dl = (rk[j] >> 13) & 255, r = rk[j] & 8191;
        int slot = gbase[b] + r;
        if (slot >= FINE_CAP) continue;
        unsigned pay = ((unsigned)ei[e] << 16) |
                       (unsigned)__half_as_ushort(__float2half(ea[e]));
        ebuk[(size_t)b * FINE_CAP + slot] = make_uint2(pay, (unsigned)dl);
    }
}

// ---------- per-bucket fine sort -> node CSR + node-sorted ep4 ----------
__global__ void __launch_bounds__(256)
bucket_fine(const uint2* __restrict__ ebuk,
            const int* __restrict__ bnext,
            unsigned* __restrict__ ep4,
            int* __restrict__ starts, int* __restrict__ deg) {
    __shared__ unsigned sorted[FINE_CAP];
    __shared__ int cntN[256], offN[256], nxtN[256];
    __shared__ int wsum[4];
    int b = blockIdx.x;
    int base = b * FINE_CAP;
    int count = bnext[b];
    if (count > FINE_CAP) count = FINE_CAP;
    int tid = threadIdx.x;
    cntN[tid] = 0;
    __syncthreads();
    for (int i = tid; i < count; i += 256)
        atomicAdd(&cntN[ebuk[base + i].y], 1);
    __syncthreads();
    int lane = tid & 63, wid = tid >> 6;
    int v = cntN[tid], incl = v;
#pragma unroll
    for (int off = 1; off < 64; off <<= 1) {
        int t = __shfl_up(incl, off, 64);
        if (lane >= off) incl += t;
    }
    if (lane == 63) wsum[wid] = incl;
    __syncthreads();
    int woff = 0;
    for (int w = 0; w < wid; ++w) woff += wsum[w];
    int excl = woff + incl - v;
    offN[tid] = excl;
    nxtN[tid] = 0;
    int n = (b << 8) + tid;
    if (n < N_NODES) { starts[n] = base + excl; deg[n] = v; }
    __syncthreads();
    for (int i = tid; i < count; i += 256) {
        uint2 e = ebuk[base + i];
        int r = atomicAdd(&nxtN[e.y], 1);
        sorted[offN[e.y] + r] = e.x;
    }
    __syncthreads();
    for (int i = tid; i < count; i += 256)
        ep4[base + i] = sorted[i];
}

#define UNPACK_ATTR(P) __half2float(__ushort_as_half((unsigned short)((P) & 0xffffu)))

// ---------- conv1 aggregation: writes xs[n][32] = (x + agg, zero-padded) ----------
__global__ void agg1_kernel(const float* __restrict__ x,
                            const int* __restrict__ starts,
                            const int* __restrict__ deg,
                            const unsigned* __restrict__ ep4,
                            const float* __restrict__ e1w,
                            const float* __restrict__ e1b,
                            float* __restrict__ xs) {
    int n = blockIdx.x * (blockDim.x >> 6) + (threadIdx.x >> 6);
    int lane = threadIdx.x & 63;
    if (n >= N_NODES) return;
    int slot = lane >> 4;
    int f = lane & 15;
    int s0 = starts[n], dg = deg[n];
    bool act = f < F_IN;
    float wf = act ? e1w[f] : 0.f;
    float bf = act ? e1b[f] : 0.f;
    float acc = 0.f;
    int j = slot;
    for (; j + 12 < dg; j += 16) {
        unsigned pa = ep4[s0 + j];
        unsigned pb = ep4[s0 + j + 4];
        unsigned pc = ep4[s0 + j + 8];
        unsigned pd = ep4[s0 + j + 12];
        float xa_ = act ? x[(pa >> 16) * F_IN + f] : 0.f;
        float xb_ = act ? x[(pb >> 16) * F_IN + f] : 0.f;
        float xc_ = act ? x[(pc >> 16) * F_IN + f] : 0.f;
        float xd_ = act ? x[(pd >> 16) * F_IN + f] : 0.f;
        if (act) {
            acc += fmaxf(xa_ + UNPACK_ATTR(pa) * wf + bf, 0.f)
                 + fmaxf(xb_ + UNPACK_ATTR(pb) * wf + bf, 0.f)
                 + fmaxf(xc_ + UNPACK_ATTR(pc) * wf + bf, 0.f)
                 + fmaxf(xd_ + UNPACK_ATTR(pd) * wf + bf, 0.f);
        }
    }
    for (; j < dg; j += 4) {
        unsigned p = ep4[s0 + j];
        float xv = act ? x[(p >> 16) * F_IN + f] : 0.f;
        float m = xv + UNPACK_ATTR(p) * wf + bf;
        acc += act ? fmaxf(m, 0.f) : 0.f;
    }
    acc += __shfl_xor(acc, 16, 64);
    acc += __shfl_xor(acc, 32, 64);
    if (lane < 32)
        xs[n * 32 + lane] = (lane < F_IN) ? x[n * F_IN + lane] + acc : 0.f;
}

__device__ __forceinline__ void split8(const float* __restrict__ v,
                                       f16x8& hi, f16x8& lo) {
#pragma unroll
    for (int j = 0; j < 8; ++j) {
        _Float16 h = (_Float16)v[j];
        hi[j] = h;
        lo[j] = (_Float16)(v[j] - (float)h);
    }
}

#define TILE3(C, A0H, A0L, A1H, A1L, PH, PL, T) do {                          \
        f16x8 b0h = *(const f16x8*)((PH) + (((T) * 2 + 0) * 64 + lane) * 8);  \
        f16x8 b0l = *(const f16x8*)((PL) + (((T) * 2 + 0) * 64 + lane) * 8);  \
        f16x8 b1h = *(const f16x8*)((PH) + (((T) * 2 + 1) * 64 + lane) * 8);  \
        f16x8 b1l = *(const f16x8*)((PL) + (((T) * 2 + 1) * 64 + lane) * 8);  \
        C = __builtin_amdgcn_mfma_f32_16x16x32_f16(A0H, b0h, C, 0, 0, 0);     \
        C = __builtin_amdgcn_mfma_f32_16x16x32_f16(A0L, b0h, C, 0, 0, 0);     \
        C = __builtin_amdgcn_mfma_f32_16x16x32_f16(A0H, b0l, C, 0, 0, 0);     \
        C = __builtin_amdgcn_mfma_f32_16x16x32_f16(A1H, b1h, C, 0, 0, 0);     \
        C = __builtin_amdgcn_mfma_f32_16x16x32_f16(A1L, b1h, C, 0, 0, 0);     \
        C = __builtin_amdgcn_mfma_f32_16x16x32_f16(A1H, b1l, C, 0, 0, 0);     \
    } while (0)

// ---------- conv1 node MLP via split-fp16 MFMA ----------
__global__ void node1_kernel(const float* __restrict__ xs,
                             const __half* __restrict__ pk1Ah, const __half* __restrict__ pk1Al,
                             const float* __restrict__ b1a,
                             const __half* __restrict__ pk1Bh, const __half* __restrict__ pk1Bl,
                             const float* __restrict__ b1b,
                             __half* __restrict__ h1lo,
                             __half* __restrict__ h1hi) {
    __shared__ float hbuf[4][16][68];
    int wv = threadIdx.x >> 6;
    int lane = threadIdx.x & 63;
    int gwave = blockIdx.x * 4 + wv;
    bool active = gwave < (N_NODES / 16);
    int base = active ? gwave * 16 : 0;
    int m = lane & 15, q = lane >> 4;
    const _Float16* pAh = (const _Float16*)pk1Ah;
    const _Float16* pAl = (const _Float16*)pk1Al;
    const _Float16* pBh = (const _Float16*)pk1Bh;
    const _Float16* pBl = (const _Float16*)pk1Bl;

    f16x8 ah, al;
    split8(xs + (size_t)(base + m) * 32 + q * 8, ah, al);
#pragma unroll
    for (int t = 0; t < 4; ++t) {
        f32x4 c = {0.f, 0.f, 0.f, 0.f};
        f16x8 bh = *(const f16x8*)(pAh + (t * 64 + lane) * 8);
        f16x8 bl = *(const f16x8*)(pAl + (t * 64 + lane) * 8);
        c = __builtin_amdgcn_mfma_f32_16x16x32_f16(ah, bh, c, 0, 0, 0);
        c = __builtin_amdgcn_mfma_f32_16x16x32_f16(al, bh, c, 0, 0, 0);
        c = __builtin_amdgcn_mfma_f32_16x16x32_f16(ah, bl, c, 0, 0, 0);
        float bias = b1a[t * 16 + m];
#pragma unroll
        for (int r = 0; r < 4; ++r)
            hbuf[wv][q * 4 + r][t * 16 + m] = fmaxf(c[r] + bias, 0.f);
    }
    __syncthreads();
    f16x8 a0h, a0l, a1h, a1l;
    split8(&hbuf[wv][m][q * 8], a0h, a0l);
    split8(&hbuf[wv][m][32 + q * 8], a1h, a1l);
    float tmp[4][4];
#pragma unroll
    for (int t = 0; t < 4; ++t) {
        f32x4 c = {0.f, 0.f, 0.f, 0.f};
        TILE3(c, a0h, a0l, a1h, a1l, pBh, pBl, t);
        float bias = b1b[t * 16 + m];
#pragma unroll
        for (int r = 0; r < 4; ++r)
            tmp[t][r] = fmaxf(c[r] + bias, 0.f);
    }
    __syncthreads();
#pragma unroll
    for (int t = 0; t < 4; ++t)
#pragma unroll
        for (int r = 0; r < 4; ++r)
            hbuf[wv][q * 4 + r][t * 16 + m] = tmp[t][r];
    __syncthreads();
    if (active) {
        int nn = lane >> 2, part = lane & 3;
        f16x8 vlo, vhi;
        const float* rlo = &hbuf[wv][nn][part * 8];
        const float* rhi = &hbuf[wv][nn][32 + part * 8];
#pragma unroll
        for (int j = 0; j < 8; ++j) {
            vlo[j] = (_Float16)rlo[j];
            vhi[j] = (_Float16)rhi[j];
        }
        *(f16x8*)(h1lo + (size_t)(base + nn) * 32 + part * 8) = vlo;
        *(f16x8*)(h1hi + (size_t)(base + nn) * 32 + part * 8) = vhi;
    }
}

// ---------- conv2 aggregation phase (L2-resident 3.2MB half) ----------
__global__ void aggphase_kernel(const __half* __restrict__ harr,
                                const int* __restrict__ starts,
                                const int* __restrict__ deg,
                                const unsigned* __restrict__ ep4,
                                const float* __restrict__ ew,
                                const float* __restrict__ eb,
                                float* __restrict__ htot, int foff) {
    int n = blockIdx.x * (blockDim.x >> 6) + (threadIdx.x >> 6);
    int lane = threadIdx.x & 63;
    if (n >= N_NODES) return;
    int half = lane >> 5;
    int fh = lane & 31;
    int s0 = starts[n], dg = deg[n];
    const unsigned* ep = ep4 + s0;
    float wf = ew[fh], bf = eb[fh];
    float acc = 0.f;
    int j = 0;
#define EDGE1(P, V) acc += fmaxf((V) + UNPACK_ATTR(P) * wf + bf, 0.f)
    for (; j + 16 <= dg; j += 16) {
        unsigned p0 = ep[j +  0 + half], p1 = ep[j +  2 + half];
        unsigned p2 = ep[j +  4 + half], p3 = ep[j +  6 + half];
        unsigned p4 = ep[j +  8 + half], p5 = ep[j + 10 + half];
        unsigned p6 = ep[j + 12 + half], p7 = ep[j + 14 + half];
        float v0 = __half2float(harr[(p0 >> 16) * 32 + fh]);
        float v1 = __half2float(harr[(p1 >> 16) * 32 + fh]);
        float v2 = __half2float(harr[(p2 >> 16) * 32 + fh]);
        float v3 = __half2float(harr[(p3 >> 16) * 32 + fh]);
        float v4 = __half2float(harr[(p4 >> 16) * 32 + fh]);
        float v5 = __half2float(harr[(p5 >> 16) * 32 + fh]);
        float v6 = __half2float(harr[(p6 >> 16) * 32 + fh]);
        float v7 = __half2float(harr[(p7 >> 16) * 32 + fh]);
        EDGE1(p0, v0); EDGE1(p1, v1); EDGE1(p2, v2); EDGE1(p3, v3);
        EDGE1(p4, v4); EDGE1(p5, v5); EDGE1(p6, v6); EDGE1(p7, v7);
    }
    for (; j + 2 <= dg; j += 2) {
        unsigned p = ep[j + half];
        float v = __half2float(harr[(p >> 16) * 32 + fh]);
        EDGE1(p, v);
    }
    if (j < dg && half == 0) {
        unsigned p = ep[j];
        float v = __half2float(harr[(p >> 16) * 32 + fh]);
        EDGE1(p, v);
    }
#undef EDGE1
    acc += __shfl_xor(acc, 32, 64);
    if (half == 0) {
        float h1v = __half2float(harr[n * 32 + fh]);
        htot[(size_t)n * 64 + foff + fh] = h1v + acc;
    }
}

// ---------- node2 via split-fp16 MFMA; writes pi only ----------
__global__ void node2_kernel(const float* __restrict__ htot,
                             const __half* __restrict__ pkAh, const __half* __restrict__ pkAl,
                             const float* __restrict__ b2a,
                             const __half* __restrict__ pkBh, const __half* __restrict__ pkBl,
                             const float* __restrict__ b2b,
                             const __half* __restrict__ pkRh, const __half* __restrict__ pkRl,
                             const float* __restrict__ br1,
                             const float* __restrict__ wr2,
                             const float* __restrict__ br2,
                             const int* __restrict__ term,
                             float* __restrict__ pi) {
    __shared__ float hbuf[4][16][68];
    int wv = threadIdx.x >> 6;
    int lane = threadIdx.x & 63;
    int gwave = blockIdx.x * 4 + wv;
    bool active = gwave < (N_NODES / 16);
    int base = active ? gwave * 16 : 0;
    int m = lane & 15, q = lane >> 4;
    const _Float16* pAh = (const _Float16*)pkAh;
    const _Float16* pAl = (const _Float16*)pkAl;
    const _Float16* pBh = (const _Float16*)pkBh;
    const _Float16* pBl = (const _Float16*)pkBl;
    const _Float16* pRh = (const _Float16*)pkRh;
    const _Float16* pRl = (const _Float16*)pkRl;

    f16x8 a0h, a0l, a1h, a1l;
    {
        const float* hrow = htot + (size_t)(base + m) * 64;
        split8(hrow + q * 8, a0h, a0l);
        split8(hrow + 32 + q * 8, a1h, a1l);
    }
#pragma unroll
    for (int t = 0; t < 4; ++t) {
        f32x4 c = {0.f, 0.f, 0.f, 0.f};
        TILE3(c, a0h, a0l, a1h, a1l, pAh, pAl, t);
        float bias = b2a[t * 16 + m];
#pragma unroll
        for (int r = 0; r < 4; ++r)
            hbuf[wv][q * 4 + r][t * 16 + m] = fmaxf(c[r] + bias, 0.f);
    }
    __syncthreads();
    split8(&hbuf[wv][m][q * 8], a0h, a0l);
    split8(&hbuf[wv][m][32 + q * 8], a1h, a1l);
    float tmp[4][4];
#pragma unroll
    for (int t = 0; t < 4; ++t) {
        f32x4 c = {0.f, 0.f, 0.f, 0.f};
        TILE3(c, a0h, a0l, a1h, a1l, pBh, pBl, t);
        float bias = b2b[t * 16 + m];
#pragma unroll
        for (int r = 0; r < 4; ++r)
            tmp[t][r] = fmaxf(c[r] + bias, 0.f);
    }
    __syncthreads();
#pragma unroll
    for (int t = 0; t < 4; ++t)
#pragma unroll
        for (int r = 0; r < 4; ++r)
            hbuf[wv][q * 4 + r][t * 16 + m] = tmp[t][r];
    __syncthreads();
    split8(&hbuf[wv][m][q * 8], a0h, a0l);
    split8(&hbuf[wv][m][32 + q * 8], a1h, a1l);
    float partial[4] = {0.f, 0.f, 0.f, 0.f};
#pragma unroll
    for (int t = 0; t < 2; ++t) {
        f32x4 c = {0.f, 0.f, 0.f, 0.f};
        TILE3(c, a0h, a0l, a1h, a1l, pRh, pRl, t);
        float bias = br1[t * 16 + m];
        float wv2 = wr2[t * 16 + m];
#pragma unroll
        for (int r = 0; r < 4; ++r)
            partial[r] += fmaxf(c[r] + bias, 0.f) * wv2;
    }
#pragma unroll
    for (int off = 1; off < 16; off <<= 1) {
        partial[0] += __shfl_xor(partial[0], off, 64);
        partial[1] += __shfl_xor(partial[1], off, 64);
        partial[2] += __shfl_xor(partial[2], off, 64);
        partial[3] += __shfl_xor(partial[3], off, 64);
    }
    if (active && m == 0) {
#pragma unroll
        for (int r = 0; r < 4; ++r) {
            int n = base + q * 4 + r;
            float z = partial[r] + br2[0];
            float sig = 1.f / (1.f + expf(-z));
            pi[n] = sig * (1.f - (float)term[n]);
        }
    }
}

// ---------- segmented te reduction (batch sorted) ----------
__global__ void te_kernel(const float* __restrict__ pi,
                          const float* __restrict__ ccost,
                          const int* __restrict__ batch,
                          float* __restrict__ te) {
    __shared__ float tg[N_GRAPHS];
    for (int i = threadIdx.x; i < N_GRAPHS; i += 1024) tg[i] = 0.f;
    __syncthreads();
    int n = blockIdx.x * 1024 + threadIdx.x;
    if (n < N_NODES) atomicAdd(&tg[batch[n]], pi[n] * ccost[n]);
    __syncthreads();
    for (int i = threadIdx.x; i < N_GRAPHS; i += 1024)
        if (tg[i] != 0.f) atomicAdd(&te[i], tg[i]);
}

__global__ void final_kernel(const float* __restrict__ pi,
                             const int* __restrict__ batch,
                             const float* __restrict__ Btot,
                             const float* __restrict__ te,
                             float* __restrict__ out) {
    int n = blockIdx.x * blockDim.x + threadIdx.x;
    if (n >= N_NODES) return;
    int b = batch[n];
    float ratio = fminf(Btot[b] / (te[b] + 1e-12f), 1.f);
    out[n] = pi[n] * ratio;
}

extern "C" void kernel_launch(void* const* d_in, const int* in_sizes, int n_in,
                              void* d_out, int out_size, void* d_ws, size_t ws_size,
                              hipStream_t stream) {
    const float* x     = (const float*)d_in[0];
    const int*   ei    = (const int*)d_in[1];
    const float* ea    = (const float*)d_in[2];
    const int*   batch = (const int*)d_in[3];
    const float* Btot  = (const float*)d_in[4];
    const int*   term  = (const int*)d_in[5];
    const float* ccost = (const float*)d_in[6];
    const float* e1w   = (const float*)d_in[7];
    const float* e1b   = (const float*)d_in[8];
    const float* w1a   = (const float*)d_in[9];
    const float* b1a   = (const float*)d_in[10];
    const float* w1b   = (const float*)d_in[11];
    const float* b1b   = (const float*)d_in[12];
    const float* e2w   = (const float*)d_in[13];
    const float* e2b   = (const float*)d_in[14];
    const float* w2a   = (const float*)d_in[15];
    const float* b2a   = (const float*)d_in[16];
    const float* w2b   = (const float*)d_in[17];
    const float* b2b   = (const float*)d_in[18];
    const float* wr1   = (const float*)d_in[19];
    const float* br1   = (const float*)d_in[20];
    const float* wr2   = (const float*)d_in[21];
    const float* br2   = (const float*)d_in[22];

    char* p = (char*)d_ws;
    int*      bnext  = (int*)p;      p += sizeof(int)      * 256;       // zeroed
    float*    te     = (float*)p;    p += sizeof(float)    * N_GRAPHS;  // zeroed
    int*      starts = (int*)p;      p += sizeof(int)      * N_NODES;
    int*      deg    = (int*)p;      p += sizeof(int)      * N_NODES;
    p = (char*)(((size_t)p + 15) & ~(size_t)15);
    uint2*    ebuk   = (uint2*)p;    p += sizeof(uint2)    * (size_t)N_BUCKETS * FINE_CAP;
    unsigned* ep4    = (unsigned*)p; p += sizeof(unsigned) * (size_t)N_BUCKETS * FINE_CAP;
    __half*   h1lo   = (__half*)p;   p += sizeof(__half)   * (size_t)N_NODES * 32;
    __half*   h1hi   = (__half*)p;   p += sizeof(__half)   * (size_t)N_NODES * 32;
    float*    htot   = (float*)p;    p += sizeof(float)    * (size_t)N_NODES * 64;
    float*    xs     = (float*)p;    p += sizeof(float)    * (size_t)N_NODES * 32;
    float*    pi     = (float*)p;    p += sizeof(float)    * N_NODES;
    __half*   pk1Ah  = (__half*)p;   p += sizeof(__half)   * 2048;
    __half*   pk1Al  = (__half*)p;   p += sizeof(__half)   * 2048;
    __half*   pk1Bh  = (__half*)p;   p += sizeof(__half)   * 4096;
    __half*   pk1Bl  = (__half*)p;   p += sizeof(__half)   * 4096;
    __half*   pkAh   = (__half*)p;   p += sizeof(__half)   * 4096;
    __half*   pkAl   = (__half*)p;   p += sizeof(__half)   * 4096;
    __half*   pkBh   = (__half*)p;   p += sizeof(__half)   * 4096;
    __half*   pkBl   = (__half*)p;   p += sizeof(__half)   * 4096;
    __half*   pkRh   = (__half*)p;   p += sizeof(__half)   * 2048;
    __half*   pkRl   = (__half*)p;   p += sizeof(__half)   * 2048;
    float*    out    = (float*)d_out;

    hipMemsetAsync(d_ws, 0, sizeof(int) * 256 + sizeof(float) * N_GRAPHS, stream);

    bucket_scatter<<<1 + N_SBLK, 256, 0, stream>>>(ei, ea, bnext, ebuk,
                                                   w1a, w1b, w2a, w2b, wr1,
                                                   pk1Ah, pk1Al, pk1Bh, pk1Bl,
                                                   pkAh, pkAl, pkBh, pkBl, pkRh, pkRl);
    bucket_fine<<<N_BUCKETS, 256, 0, stream>>>(ebuk, bnext, ep4, starts, deg);
    agg1_kernel<<<(N_NODES + 3) / 4, 256, 0, stream>>>(x, starts, deg, ep4, e1w, e1b, xs);
    node1_kernel<<<(N_NODES / 16 + 3) / 4, 256, 0, stream>>>(xs, pk1Ah, pk1Al, b1a,
                                                             pk1Bh, pk1Bl, b1b,
                                                             h1lo, h1hi);
    aggphase_kernel<<<(N_NODES + 3) / 4, 256, 0, stream>>>(h1lo, starts, deg, ep4,
                                                           e2w, e2b, htot, 0);
    aggphase_kernel<<<(N_NODES + 3) / 4, 256, 0, stream>>>(h1hi, starts, deg, ep4,
                                                           e2w + 32, e2b + 32, htot, 32);
    node2_kernel<<<(N_NODES / 16 + 3) / 4, 256, 0, stream>>>(htot,
                                                             pkAh, pkAl, b2a,
                                                             pkBh, pkBl, b2b,
                                                             pkRh, pkRl, br1,
                                                             wr2, br2, term, pi);
    te_kernel<<<(N_NODES + 1023) / 1024, 1024, 0, stream>>>(pi, ccost, batch, te);
    final_kernel<<<(N_NODES + 255) / 256, 256, 0, stream>>>(pi, batch, Btot, te, out);
}